// Round 5
// baseline (377.120 us; speedup 1.0000x reference)
//
#include <hip/hip_runtime.h>

#define LENF 15
#define NZ   1e-5f

typedef float f32x2 __attribute__((ext_vector_type(2)));

struct R3 { float p, t, e; };   // 12B record -> global_load_dwordx3

struct Cell {
  float ddf, Tbm, wrf, Tbf, Kf, exp_fe, ET_eff, c_run, c_v2p, c_vad, c_phr,
        vml, inv_vml;
  float sog, wis, vad, phr;
  f32x2 wv[LENF];
  f32x2 acc[LENF];
};

__device__ __forceinline__ void init_cell(Cell& c, const float* pp) {
  float P0[16];
#pragma unroll
  for (int i = 0; i < 16; ++i) P0[i] = pp[i];
  c.ddf    = P0[0]  * 40.f;
  c.Tbm    = P0[1]  * 5.f  - 2.f;
  c.wrf    = P0[2]  * 0.5f;
  c.Tbf    = P0[3]  * 7.f  - 5.f;
  c.Kf     = P0[4]  * 5.f;
  c.exp_fe = P0[5];
  c.ET_eff = P0[6];
  c.c_run  = P0[7];
  c.c_v2p  = P0[8]  * (0.02f - 1e-5f) + 1e-5f;
  c.c_vad  = P0[9]  * 0.1f;
  c.c_phr  = P0[10] * (0.01f - 1e-5f) + 1e-5f;
  c.vml    = P0[11] * (500.f - 0.001f) + 0.001f;
  c.inv_vml = 1.f / c.vml;
  const float a1 = P0[12] * (20.f - 0.3f)  + 0.3f;
  const float b1 = P0[13] * (5.f  - 0.01f) + 0.01f;
  const float a2 = P0[14] * (13.f - 0.5f)  + 0.5f;
  const float b2 = P0[15] * (1.5f - 0.15f) + 0.15f;

  // gamma UH weights; lgamma/theta terms cancel under normalization
  float lw1[LENF], lw2[LENF];
  float m1 = -1e30f, m2 = -1e30f;
  const float ib1 = 1.f / b1, ib2 = 1.f / b2;
#pragma unroll
  for (int l = 0; l < LENF; ++l) {
    float tt = l + 0.5f;
    float lt = __logf(tt);
    lw1[l] = (a1 - 1.f) * lt - tt * ib1;
    lw2[l] = (a2 - 1.f) * lt - tt * ib2;
    m1 = fmaxf(m1, lw1[l]);
    m2 = fmaxf(m2, lw2[l]);
  }
  float s1 = 0.f, s2 = 0.f;
  float t1[LENF], t2[LENF];
#pragma unroll
  for (int l = 0; l < LENF; ++l) {
    t1[l] = __expf(lw1[l] - m1); s1 += t1[l];
    t2[l] = __expf(lw2[l] - m2); s2 += t2[l];
  }
  const float r1 = 1.f / s1, r2 = 1.f / s2;
#pragma unroll
  for (int l = 0; l < LENF; ++l) { c.wv[l].x = t1[l] * r1; c.wv[l].y = t2[l] * r2; }

  c.sog = NZ; c.wis = NZ; c.vad = NZ; c.phr = NZ;
#pragma unroll
  for (int l = 0; l < LENF; ++l) { c.acc[l].x = 0.f; c.acc[l].y = 0.f; }
}

// One recurrence step + fused 15-tap conv. `i` must be a compile-time
// constant after unrolling (static acc indices). Returns out[t].
// Conv ring is zeroing-free: slot (i+14)%15 (consumed at step i-1) is
// OVERWRITTEN by the l=14 tap (pk_mul), all other taps accumulate (pk_fma).
__device__ __forceinline__ float step_cell(Cell& c, R3 r, int i) {
  float p = r.p, tm = r.t, pe = r.e;
  float rain = (tm >= 0.f) ? p : 0.f;
  float snow = p - rain;
  float pot_freeze = c.Kf * __builtin_amdgcn_exp2f(
      c.exp_fe * __builtin_amdgcn_logf(fmaxf(c.Tbf - tm, NZ)));
  float freeze = fminf(pot_freeze, c.wis);
  c.wis -= freeze;
  float sos = c.sog + freeze + snow;
  float melt = fminf(fmaxf(c.ddf * (tm - c.Tbm), 0.f), sos);
  c.sog = sos - melt;
  float retention = c.wrf * c.sog;
  float wtmp = c.wis + melt + rain;
  float avail = fmaxf(wtmp - retention, 0.f);
  c.wis = fminf(wtmp, retention);   // == avail>0 ? retention : wtmp
  float ratio = c.vad * c.inv_vml;
  float ht0 = c.c_run * ratio * avail;
  float infil = avail - ht0;
  float ht1 = c.c_v2p * ratio * c.vad;
  float ht2 = c.c_vad * c.vad;
  float ht3 = c.c_phr * c.phr;
  float aet = fminf(c.ET_eff * pe, c.vad);
  c.vad = c.vad + infil - aet - ht1 - ht2;
  float overflow = fmaxf(c.vad - c.vml, 0.f);
  c.vad = fminf(fmaxf(c.vad, NZ), c.vml);   // v_med3_f32
  ht0 += overflow;
  c.phr = fmaxf(c.phr + ht1 - ht3, NZ);

  f32x2 q; q.x = ht0; q.y = ht2 + ht3;
  f32x2 ov = c.acc[i] + c.wv[0] * q;        // out accumulate (pk_fma)
#pragma unroll
  for (int l = 1; l < LENF - 1; ++l) {
    int s = i + l; if (s >= LENF) s -= LENF;
    c.acc[s] += c.wv[l] * q;                // pk_fma
  }
  {
    int s = i + LENF - 1; if (s >= LENF) s -= LENF;
    c.acc[s] = c.wv[LENF - 1] * q;          // overwrite: zeroing-free ring
  }
  return ov.x + ov.y;
}

__global__ __launch_bounds__(64, 1) void exphydro_kernel(
    const float* __restrict__ x,      // (T, G, 3)
    const float* __restrict__ params, // (G, 16)
    float* __restrict__ out,          // (T, G)
    int G, int T)
{
  const int half = (G + 1) >> 1;
  int g = blockIdx.x * 64 + threadIdx.x;
  if (g >= half) return;
  const int g2 = g + half;
  const bool hasY = (g2 < G);
  const int g2s = hasY ? g2 : (G - 1);     // safe index for loads

  Cell cx, cy;
  init_cell(cx, params + (size_t)g * 16);
  init_cell(cy, params + (size_t)g2s * 16);

  const unsigned Gu = (unsigned)G;
  const R3* xgx = (const R3*)x + g;        // record idx = t*G + g (<2^31 B)
  const R3* xgy = (const R3*)x + g2s;
  float* ox = out + g;
  float* oy = out + g2s;

  R3 AX[LENF], BX[LENF], AY[LENF], BY[LENF];

  const int nb   = T / LENF;
  const int tail = T - nb * LENF;

#define LOAD(BUF, XG, blk)                                            \
  {                                                                   \
    unsigned b0_ = (unsigned)(blk) * (unsigned)LENF * Gu;             \
    _Pragma("unroll")                                                 \
    for (int j = 0; j < LENF; ++j) BUF[j] = (XG)[b0_ + (unsigned)j * Gu]; \
  }

#define LOAD_G(BUF, XG, blk)                                          \
  {                                                                   \
    unsigned b0_ = (unsigned)(blk) * (unsigned)LENF * Gu;             \
    _Pragma("unroll")                                                 \
    for (int j = 0; j < LENF; ++j) {                                  \
      if ((blk) * LENF + j < T) BUF[j] = (XG)[b0_ + (unsigned)j * Gu];\
      else { BUF[j].p = 0.f; BUF[j].t = 0.f; BUF[j].e = 0.f; }        \
    }                                                                 \
  }

  // Interleave the two cells' steps -> two independent dependency chains
  // fill each other's latency bubbles (1 wave/SIMD, no TLP available).
#define PAIR_BLOCK(BUFX, BUFY)                                        \
  {                                                                   \
    _Pragma("unroll")                                                 \
    for (int i = 0; i < LENF; ++i) {                                  \
      float vx = step_cell(cx, BUFX[i], i);                           \
      float vy = step_cell(cy, BUFY[i], i);                           \
      *ox = vx;                                                       \
      if (hasY) *oy = vy;                                             \
      ox += G; oy += G;                                               \
    }                                                                 \
  }

#define PAIR_BLOCK_G(BUFX, BUFY, t0)                                  \
  {                                                                   \
    _Pragma("unroll")                                                 \
    for (int i = 0; i < LENF; ++i) {                                  \
      if ((t0) + i < T) {                                             \
        float vx = step_cell(cx, BUFX[i], i);                         \
        float vy = step_cell(cy, BUFY[i], i);                         \
        *ox = vx;                                                     \
        if (hasY) *oy = vy;                                           \
        ox += G; oy += G;                                             \
      }                                                               \
    }                                                                 \
  }

  if (nb > 0) { LOAD(AX, xgx, 0); LOAD(AY, xgy, 0); }

  int k = 0;
  while (k + 2 <= nb) {
    LOAD(BX, xgx, k + 1); LOAD(BY, xgy, k + 1);   // prefetch next block
    PAIR_BLOCK(AX, AY);
    if (k + 2 < nb) { LOAD(AX, xgx, k + 2); LOAD(AY, xgy, k + 2); }
    PAIR_BLOCK(BX, BY);
    k += 2;
  }
  if (k < nb) {                   // nb odd: final full block already in A
    PAIR_BLOCK(AX, AY);
  }
  if (tail > 0) {                 // generic tail (empty at T=1095)
    LOAD_G(AX, xgx, nb); LOAD_G(AY, xgy, nb);
    PAIR_BLOCK_G(AX, AY, nb * LENF);
  }

#undef LOAD
#undef LOAD_G
#undef PAIR_BLOCK
#undef PAIR_BLOCK_G
}

extern "C" void kernel_launch(void* const* d_in, const int* in_sizes, int n_in,
                              void* d_out, int out_size, void* d_ws, size_t ws_size,
                              hipStream_t stream) {
  const float* x      = (const float*)d_in[0];
  const float* params = (const float*)d_in[1];
  float* out          = (float*)d_out;

  int G = in_sizes[1] / 16;               // 15000
  int T = in_sizes[0] / (G * 3);          // 1095

  int half  = (G + 1) / 2;                // 2 cells per thread
  int block = 64;
  int grid  = (half + block - 1) / block; // 118 blocks -> 118 waves
  exphydro_kernel<<<grid, block, 0, stream>>>(x, params, out, G, T);
}

// Round 6
// 357.562 us; speedup vs baseline: 1.0547x; 1.0547x over previous
//
#include <hip/hip_runtime.h>

#define LENF 15
#define BLK  5
#define NZ   1e-5f

typedef float f32x2 __attribute__((ext_vector_type(2)));

struct R3 { float p, t, e; };   // 12B record -> global_load_dwordx3

// Per-cell persistent state: 13 params + 4 state + 15 f32x2 weights +
// 14 f32x2 FIR partial sums  =  75 VGPRs.
struct Cell {
  float ddf, Tbm, wrf, Tbf, Kf, exp_fe, ET_eff, c_run, c_v2p, c_vad, c_phr,
        vml, inv_vml;
  float sog, wis, vad, phr;
  f32x2 wv[LENF];        // (w1[l], w2[l])
  f32x2 s[LENF - 1];     // transposed-FIR delay line
};

__device__ __forceinline__ void init_cell(Cell& c, const float* pp) {
  float P0[16];
#pragma unroll
  for (int i = 0; i < 16; ++i) P0[i] = pp[i];
  c.ddf    = P0[0]  * 40.f;
  c.Tbm    = P0[1]  * 5.f  - 2.f;
  c.wrf    = P0[2]  * 0.5f;
  c.Tbf    = P0[3]  * 7.f  - 5.f;
  c.Kf     = P0[4]  * 5.f;
  c.exp_fe = P0[5];
  c.ET_eff = P0[6];
  c.c_run  = P0[7];
  c.c_v2p  = P0[8]  * (0.02f - 1e-5f) + 1e-5f;
  c.c_vad  = P0[9]  * 0.1f;
  c.c_phr  = P0[10] * (0.01f - 1e-5f) + 1e-5f;
  c.vml    = P0[11] * (500.f - 0.001f) + 0.001f;
  c.inv_vml = 1.f / c.vml;
  const float a1 = P0[12] * (20.f - 0.3f)  + 0.3f;
  const float b1 = P0[13] * (5.f  - 0.01f) + 0.01f;
  const float a2 = P0[14] * (13.f - 0.5f)  + 0.5f;
  const float b2 = P0[15] * (1.5f - 0.15f) + 0.15f;

  // gamma UH weights; lgamma/theta terms cancel under normalization
  float lw1[LENF], lw2[LENF];
  float m1 = -1e30f, m2 = -1e30f;
  const float ib1 = 1.f / b1, ib2 = 1.f / b2;
#pragma unroll
  for (int l = 0; l < LENF; ++l) {
    float tt = l + 0.5f;
    float lt = __logf(tt);
    lw1[l] = (a1 - 1.f) * lt - tt * ib1;
    lw2[l] = (a2 - 1.f) * lt - tt * ib2;
    m1 = fmaxf(m1, lw1[l]);
    m2 = fmaxf(m2, lw2[l]);
  }
  float s1 = 0.f, s2 = 0.f;
  float t1[LENF], t2[LENF];
#pragma unroll
  for (int l = 0; l < LENF; ++l) {
    t1[l] = __expf(lw1[l] - m1); s1 += t1[l];
    t2[l] = __expf(lw2[l] - m2); s2 += t2[l];
  }
  const float r1 = 1.f / s1, r2 = 1.f / s2;
#pragma unroll
  for (int l = 0; l < LENF; ++l) { c.wv[l].x = t1[l] * r1; c.wv[l].y = t2[l] * r2; }

  c.sog = NZ; c.wis = NZ; c.vad = NZ; c.phr = NZ;
#pragma unroll
  for (int l = 0; l < LENF - 1; ++l) { c.s[l].x = 0.f; c.s[l].y = 0.f; }
}

// One recurrence step + transposed-FIR conv (fixed indices, no ring phase).
__device__ __forceinline__ float step_cell(Cell& c, R3 r) {
  float p = r.p, tm = r.t, pe = r.e;
  float rain = (tm >= 0.f) ? p : 0.f;
  float snow = p - rain;
  float pot_freeze = c.Kf * __builtin_amdgcn_exp2f(
      c.exp_fe * __builtin_amdgcn_logf(fmaxf(c.Tbf - tm, NZ)));
  float freeze = fminf(pot_freeze, c.wis);
  c.wis -= freeze;
  float sos = c.sog + freeze + snow;
  float melt = fminf(fmaxf(c.ddf * (tm - c.Tbm), 0.f), sos);
  c.sog = sos - melt;
  float retention = c.wrf * c.sog;
  float wtmp = c.wis + melt + rain;
  float avail = fmaxf(wtmp - retention, 0.f);
  c.wis = fminf(wtmp, retention);   // == avail>0 ? retention : wtmp
  float ratio = c.vad * c.inv_vml;
  float ht0 = c.c_run * ratio * avail;
  float infil = avail - ht0;
  float ht1 = c.c_v2p * ratio * c.vad;
  float ht2 = c.c_vad * c.vad;
  float ht3 = c.c_phr * c.phr;
  float aet = fminf(c.ET_eff * pe, c.vad);
  c.vad = c.vad + infil - aet - ht1 - ht2;
  float overflow = fmaxf(c.vad - c.vml, 0.f);
  c.vad = fminf(fmaxf(c.vad, NZ), c.vml);   // v_med3_f32
  ht0 += overflow;
  c.phr = fmaxf(c.phr + ht1 - ht3, NZ);

  f32x2 q; q.x = ht0; q.y = ht2 + ht3;
  f32x2 o = c.s[0] + c.wv[0] * q;
#pragma unroll
  for (int l = 0; l < LENF - 2; ++l)
    c.s[l] = c.s[l + 1] + c.wv[l + 1] * q;   // pk_fma, fixed indices
  c.s[LENF - 2] = c.wv[LENF - 1] * q;
  return o.x + o.y;
}

__global__ __launch_bounds__(64, 1) void exphydro_kernel(
    const float* __restrict__ x,      // (T, G, 3)
    const float* __restrict__ params, // (G, 16)
    float* __restrict__ out,          // (T, G)
    int G, int T)
{
  const int half = (G + 1) >> 1;
  int g = blockIdx.x * 64 + threadIdx.x;
  if (g >= half) return;
  const int g2 = g + half;
  const bool hasY = (g2 < G);
  const int g2s = hasY ? g2 : (G - 1);     // safe index (dup work if G odd)

  Cell cx, cy;
  init_cell(cx, params + (size_t)g * 16);
  init_cell(cy, params + (size_t)g2s * 16);

  const unsigned Gu = (unsigned)G;
  const R3* xgx = (const R3*)x + g;        // record idx = t*G + g (<2^31 B)
  const R3* xgy = (const R3*)x + g2s;
  float* ox = out + g;
  float* oy = out + g2s;

  // chunk staging: 2 buffers x BLK records x 2 cells = 60 VGPRs
  R3 AX[BLK], AY[BLK], BX[BLK], BY[BLK];

  const int nch = T / BLK;                 // 219 for T=1095
  const int rem = T - nch * BLK;           // 0

#define LOADC(BX_, BY_, ch)                                           \
  {                                                                   \
    unsigned b0_ = (unsigned)(ch) * (unsigned)BLK * Gu;               \
    _Pragma("unroll")                                                 \
    for (int j = 0; j < BLK; ++j) {                                   \
      BX_[j] = xgx[b0_ + (unsigned)j * Gu];                           \
      BY_[j] = xgy[b0_ + (unsigned)j * Gu];                           \
    }                                                                 \
  }

  // interleave the two cells: two independent dependency chains fill
  // each other's latency bubbles (1 wave/SIMD -> no TLP available)
#define STEPC(BX_, BY_)                                               \
  {                                                                   \
    _Pragma("unroll")                                                 \
    for (int i = 0; i < BLK; ++i) {                                   \
      float vx = step_cell(cx, BX_[i]);                               \
      float vy = step_cell(cy, BY_[i]);                               \
      *ox = vx;                                                       \
      if (hasY) *oy = vy;                                             \
      ox += G; oy += G;                                               \
    }                                                                 \
  }

  if (nch > 0) LOADC(AX, AY, 0);

  int k = 0;
  while (k + 2 <= nch) {
    LOADC(BX, BY, k + 1);          // prefetch next chunk
    STEPC(AX, AY);
    if (k + 2 < nch) LOADC(AX, AY, k + 2);
    STEPC(BX, BY);
    k += 2;
  }
  if (k < nch) {                   // odd chunk count: last chunk in A
    STEPC(AX, AY);
  }
  if (rem > 0) {                   // generic tail (empty at T=1095)
    unsigned b0 = (unsigned)nch * (unsigned)BLK * Gu;
    for (int j = 0; j < rem; ++j) {
      R3 rx = xgx[b0 + (unsigned)j * Gu];
      R3 ry = xgy[b0 + (unsigned)j * Gu];
      float vx = step_cell(cx, rx);
      float vy = step_cell(cy, ry);
      *ox = vx;
      if (hasY) *oy = vy;
      ox += G; oy += G;
    }
  }

#undef LOADC
#undef STEPC
}

extern "C" void kernel_launch(void* const* d_in, const int* in_sizes, int n_in,
                              void* d_out, int out_size, void* d_ws, size_t ws_size,
                              hipStream_t stream) {
  const float* x      = (const float*)d_in[0];
  const float* params = (const float*)d_in[1];
  float* out          = (float*)d_out;

  int G = in_sizes[1] / 16;               // 15000
  int T = in_sizes[0] / (G * 3);          // 1095

  int half  = (G + 1) / 2;                // 2 cells per thread
  int block = 64;
  int grid  = (half + block - 1) / block; // 118 waves
  exphydro_kernel<<<grid, block, 0, stream>>>(x, params, out, G, T);
}